// Round 3
// baseline (25536.494 us; speedup 1.0000x reference)
//
#include <hip/hip_runtime.h>
#include <hip/hip_bf16.h>

#define TSTEPS 256
#define BATCH  64
#define NINP   64
#define NHID   4096
#define NGATE  (4 * NHID)        // 16384
#define KDIM   (NINP + NHID)     // 4160
#define NCHUNK (KDIM / 32)       // 130 chunks of 32 k-values
#define NGRP   (NGATE / 16)      // 1024 groups of 16 gate rows
#define NBLK   256

typedef __bf16 bf16x8 __attribute__((ext_vector_type(8)));
typedef float  f32x4  __attribute__((ext_vector_type(4)));
typedef unsigned short ushort_t;

__device__ __forceinline__ ushort_t f2b(float v) {
    __hip_bfloat16 h = __float2bfloat16(v);
    return *reinterpret_cast<ushort_t*>(&h);
}
__device__ __forceinline__ float sigf(float x) { return 1.f / (1.f + expf(-x)); }

// Fragment-linear layout (unchanged from R2):
//   W'[grp][chunk][lane][8] : lane = q*16 + n holds row (grp*16+n), k = chunk*32 + q*8 ..
//   A'[rt ][chunk][lane][8] : lane = q*16 + n holds batch row (rt*16+n)

__global__ void k_convert(const float* __restrict__ w_ih, const float* __restrict__ w_hh,
                          const float* __restrict__ b_ih, const float* __restrict__ b_hh,
                          ushort_t* __restrict__ Wp, float* __restrict__ bias) {
    const int grp = blockIdx.x;
    for (int i = threadIdx.x; i < 16 * KDIM; i += 256) {
        int r = i / KDIM;
        int k = i - r * KDIM;
        int g = grp * 16 + r;
        float v = (k < NINP) ? w_ih[(size_t)g * NINP + k]
                             : w_hh[(size_t)g * NHID + (k - NINP)];
        int c = k >> 5, q = (k >> 3) & 3, e = k & 7;
        Wp[((size_t)grp * NCHUNK + c) * 512 + (q * 16 + r) * 8 + e] = f2b(v);
    }
    if (threadIdx.x < 16) {
        int g = grp * 16 + threadIdx.x;
        bias[g] = b_ih[g] + b_hh[g];
    }
}

__global__ void k_init(const int* __restrict__ tokens, const float* __restrict__ emb,
                       ushort_t* __restrict__ A0, int* __restrict__ sync) {
    int idx = blockIdx.x * 256 + threadIdx.x;
    if (idx < BATCH * KDIM) {
        int b = idx / KDIM, k = idx - b * KDIM;
        float v = (k < NINP) ? emb[tokens[b] * NINP + k] : 0.f;
        int c = k >> 5, q = (k >> 3) & 3, e = k & 7;
        A0[((size_t)(b >> 4) * NCHUNK + c) * 512 + (q * 16 + (b & 15)) * 8 + e] = f2b(v);
    }
    if (idx < 2) sync[idx] = 0;   // cnt, gen
}

// ---- persistent LSTM: all 256 steps in one cooperative launch ----
__global__ __launch_bounds__(512, 2)
void k_persist(const ushort_t* __restrict__ Wp, const float* __restrict__ bias,
               ushort_t* __restrict__ A0, ushort_t* __restrict__ A1,
               float* __restrict__ out,
               const int* __restrict__ tokens, const int* __restrict__ seq_len,
               const float* __restrict__ emb, int* __restrict__ sync) {
    const int tid  = threadIdx.x;
    const int wave = tid >> 6;
    const int lane = tid & 63;
    const int bx   = blockIdx.x;
    const int j0   = bx * 16;

    int* cnt = sync;
    int* gen = sync + 1;

    __shared__ float sbuf[BATCH][66];

    // --- per-thread persistent state ---
    // epilogue cols: jl = wave, wave+8 ; batch = lane
    const int jA = j0 + wave, jB = j0 + wave + 8;
    float cA = 0.f, cB = 0.f;
    const int  slen  = seq_len[lane];
    const float bAi = bias[jA],            bBi = bias[jB];
    const float bAf = bias[NHID + jA],     bBf = bias[NHID + jB];
    const float bAg = bias[2 * NHID + jA], bBg = bias[2 * NHID + jB];
    const float bAo = bias[3 * NHID + jA], bBo = bias[3 * NHID + jB];
    // An write offsets (ushort units) for h values, fixed per thread
    size_t hoffA, hoffB;
    {
        int kk = NINP + jA;
        int c = kk >> 5, q = (kk >> 3) & 3, e = kk & 7;
        hoffA = ((size_t)(lane >> 4) * NCHUNK + c) * 512 + (q * 16 + (lane & 15)) * 8 + e;
        kk = NINP + jB;
        c = kk >> 5; q = (kk >> 3) & 3; e = kk & 7;
        hoffB = ((size_t)(lane >> 4) * NCHUNK + c) * 512 + (q * 16 + (lane & 15)) * 8 + e;
    }

    // K-chunk range per wave
    const int cstart = wave * 16 + (wave < 2 ? wave : 2);
    const int cend   = cstart + (wave < 2 ? 17 : 16);

    const ushort_t* pw0 = Wp + ((size_t)(0 * 256 + bx) * NCHUNK) * 512 + lane * 8;
    const ushort_t* pw1 = Wp + ((size_t)(1 * 256 + bx) * NCHUNK) * 512 + lane * 8;
    const ushort_t* pw2 = Wp + ((size_t)(2 * 256 + bx) * NCHUNK) * 512 + lane * 8;
    const ushort_t* pw3 = Wp + ((size_t)(3 * 256 + bx) * NCHUNK) * 512 + lane * 8;

    int lgen = 0;

    for (int t = 0; t < TSTEPS; ++t) {
        ushort_t* Ac = (t & 1) ? A1 : A0;
        ushort_t* An = (t & 1) ? A0 : A1;

        // zero reduction buffer
        for (int i = tid; i < BATCH * 66; i += 512)
            (&sbuf[0][0])[i] = 0.f;

        const ushort_t* pa0 = Ac + ((size_t)0 * NCHUNK) * 512 + lane * 8;
        const ushort_t* pa1 = Ac + ((size_t)1 * NCHUNK) * 512 + lane * 8;
        const ushort_t* pa2 = Ac + ((size_t)2 * NCHUNK) * 512 + lane * 8;
        const ushort_t* pa3 = Ac + ((size_t)3 * NCHUNK) * 512 + lane * 8;

        f32x4 acc[4][4];
        #pragma unroll
        for (int rt = 0; rt < 4; ++rt)
            #pragma unroll
            for (int gt = 0; gt < 4; ++gt)
                acc[rt][gt] = (f32x4){0.f, 0.f, 0.f, 0.f};

        #define LOADF(dstW, dstA, c)                                          \
            do {                                                              \
                size_t off = (size_t)(c) * 512;                               \
                dstW[0] = *reinterpret_cast<const bf16x8*>(pw0 + off);        \
                dstW[1] = *reinterpret_cast<const bf16x8*>(pw1 + off);        \
                dstW[2] = *reinterpret_cast<const bf16x8*>(pw2 + off);        \
                dstW[3] = *reinterpret_cast<const bf16x8*>(pw3 + off);        \
                dstA[0] = *reinterpret_cast<const bf16x8*>(pa0 + off);        \
                dstA[1] = *reinterpret_cast<const bf16x8*>(pa1 + off);        \
                dstA[2] = *reinterpret_cast<const bf16x8*>(pa2 + off);        \
                dstA[3] = *reinterpret_cast<const bf16x8*>(pa3 + off);        \
            } while (0)

        bf16x8 curW[4], curA[4], nxtW[4], nxtA[4];
        LOADF(curW, curA, cstart);

        __syncthreads();   // sbuf zeroed before any atomics land

        for (int c = cstart; c < cend - 1; ++c) {
            LOADF(nxtW, nxtA, c + 1);
            #pragma unroll
            for (int rt = 0; rt < 4; ++rt)
                #pragma unroll
                for (int gt = 0; gt < 4; ++gt)
                    acc[rt][gt] = __builtin_amdgcn_mfma_f32_16x16x32_bf16(
                        curA[rt], curW[gt], acc[rt][gt], 0, 0, 0);
            #pragma unroll
            for (int z = 0; z < 4; ++z) { curW[z] = nxtW[z]; curA[z] = nxtA[z]; }
        }
        #pragma unroll
        for (int rt = 0; rt < 4; ++rt)
            #pragma unroll
            for (int gt = 0; gt < 4; ++gt)
                acc[rt][gt] = __builtin_amdgcn_mfma_f32_16x16x32_bf16(
                    curA[rt], curW[gt], acc[rt][gt], 0, 0, 0);
        #undef LOADF

        {
            const int n = lane & 15, q = lane >> 4;
            #pragma unroll
            for (int rt = 0; rt < 4; ++rt)
                #pragma unroll
                for (int gt = 0; gt < 4; ++gt)
                    #pragma unroll
                    for (int r = 0; r < 4; ++r)
                        atomicAdd(&sbuf[rt * 16 + q * 4 + r][gt * 16 + n], acc[rt][gt][r]);
        }
        __syncthreads();

        // epilogue: batch b = lane, cols jA (jl=wave) and jB (jl=wave+8)
        {
            const int b = lane;
            const bool valid = (t < slen) || (t == 0);
            // col A
            {
                int jl = wave;
                float ig = sbuf[b][ 0 + jl] + bAi;
                float fg = sbuf[b][16 + jl] + bAf;
                float gg = sbuf[b][32 + jl] + bAg;
                float og = sbuf[b][48 + jl] + bAo;
                cA = sigf(fg) * cA + sigf(ig) * tanhf(gg);
                float hn = sigf(og) * tanhf(cA);
                if (valid) out[b * NHID + jA] = cA;
                An[hoffA] = f2b(hn);
            }
            // col B
            {
                int jl = wave + 8;
                float ig = sbuf[b][ 0 + jl] + bBi;
                float fg = sbuf[b][16 + jl] + bBf;
                float gg = sbuf[b][32 + jl] + bBg;
                float og = sbuf[b][48 + jl] + bBo;
                cB = sigf(fg) * cB + sigf(ig) * tanhf(gg);
                float hn = sigf(og) * tanhf(cB);
                if (valid) out[b * NHID + jB] = cB;
                An[hoffB] = f2b(hn);
            }
        }

        // block 0: next step's embedding rows into An
        if (bx == 0 && (t + 1) < TSTEPS) {
            for (int i = tid; i < BATCH * NINP; i += 512) {
                int b = i >> 6, k = i & 63;
                int tok = tokens[(t + 1) * BATCH + b];
                float v = emb[tok * NINP + k];
                int c = k >> 5, q = (k >> 3) & 3, e = k & 7;
                An[((size_t)(b >> 4) * NCHUNK + c) * 512 + (q * 16 + (b & 15)) * 8 + e] = f2b(v);
            }
        }

        // grid-wide barrier (skip after the final step)
        if (t + 1 < TSTEPS) {
            __syncthreads();
            if (tid == 0) {
                __threadfence();                       // release: L2 wb+inv
                if (atomicAdd(cnt, 1) == NBLK - 1) {
                    __hip_atomic_store(cnt, 0, __ATOMIC_RELAXED, __HIP_MEMORY_SCOPE_AGENT);
                    __threadfence();
                    __hip_atomic_store(gen, lgen + 1, __ATOMIC_RELEASE, __HIP_MEMORY_SCOPE_AGENT);
                } else {
                    while (__hip_atomic_load(gen, __ATOMIC_RELAXED, __HIP_MEMORY_SCOPE_AGENT) <= lgen)
                        __builtin_amdgcn_s_sleep(1);
                }
                __threadfence();                       // acquire: L2 inv
            }
            __syncthreads();
            ++lgen;
        }
    }
}

extern "C" void kernel_launch(void* const* d_in, const int* in_sizes, int n_in,
                              void* d_out, int out_size, void* d_ws, size_t ws_size,
                              hipStream_t stream) {
    const int*   tokens  = (const int*)d_in[0];
    const int*   seq_len = (const int*)d_in[1];
    const float* emb     = (const float*)d_in[2];
    const float* w_ih    = (const float*)d_in[3];
    const float* w_hh    = (const float*)d_in[4];
    const float* b_ih    = (const float*)d_in[5];
    const float* b_hh    = (const float*)d_in[6];
    float* out = (float*)d_out;

    char* ws = (char*)d_ws;
    const size_t W_BYTES    = (size_t)NGRP * NCHUNK * 512 * 2;  // 136,314,880
    const size_t BIAS_BYTES = (size_t)NGATE * 4;
    const size_t A_BYTES    = (size_t)4 * NCHUNK * 512 * 2;     // 532,480

    ushort_t* Wp   = (ushort_t*)ws;
    float*    bias = (float*)(ws + W_BYTES);
    ushort_t* A0   = (ushort_t*)(ws + W_BYTES + BIAS_BYTES);
    ushort_t* A1   = (ushort_t*)(ws + W_BYTES + BIAS_BYTES + A_BYTES);
    int*      sync = (int*)(ws + W_BYTES + BIAS_BYTES + 2 * A_BYTES);

    k_convert<<<NGRP, 256, 0, stream>>>(w_ih, w_hh, b_ih, b_hh, Wp, bias);

    int init_elems = BATCH * KDIM;
    k_init<<<(init_elems + 255) / 256, 256, 0, stream>>>(tokens, emb, A0, sync);

    void* args[] = {(void*)&Wp, (void*)&bias, (void*)&A0, (void*)&A1, (void*)&out,
                    (void*)&tokens, (void*)&seq_len, (void*)&emb, (void*)&sync};
    hipLaunchCooperativeKernel((void*)k_persist, dim3(NBLK), dim3(512), args, 0, stream);
}

// Round 4
// 19562.871 us; speedup vs baseline: 1.3054x; 1.3054x over previous
//
#include <hip/hip_runtime.h>
#include <hip/hip_bf16.h>

#define TSTEPS 256
#define BATCH  64
#define NINP   64
#define NHID   4096
#define NGATE  (4 * NHID)        // 16384
#define KDIM   (NINP + NHID)     // 4160
#define NCHUNK (KDIM / 32)       // 130 chunks of 32 k-values
#define NGRP   (NGATE / 16)      // 1024 groups of 16 gate rows
#define NBLK   256

typedef __bf16 bf16x8 __attribute__((ext_vector_type(8)));
typedef float  f32x4  __attribute__((ext_vector_type(4)));
typedef unsigned short ushort_t;

__device__ __forceinline__ ushort_t f2b(float v) {
    __hip_bfloat16 h = __float2bfloat16(v);
    return *reinterpret_cast<ushort_t*>(&h);
}
__device__ __forceinline__ float sigf(float x) { return 1.f / (1.f + expf(-x)); }

// sync layout (ints, each slot on its own 128B line):
//   master_cnt = sync[0], master_gen = sync[32]
//   shard_cnt[s] = sync[64 + 32*s], shard_gen[s] = sync[320 + 32*s]   (s = 0..7)
#define SYNC_INTS 576

// Fragment-linear layout (unchanged):
//   W'[grp][chunk][lane][8] : lane = q*16 + n holds row (grp*16+n), k = chunk*32 + q*8 ..
//   A'[rt ][chunk][lane][8] : lane = q*16 + n holds batch row (rt*16+n)

__global__ void k_convert(const float* __restrict__ w_ih, const float* __restrict__ w_hh,
                          const float* __restrict__ b_ih, const float* __restrict__ b_hh,
                          ushort_t* __restrict__ Wp, float* __restrict__ bias) {
    const int grp = blockIdx.x;
    for (int i = threadIdx.x; i < 16 * KDIM; i += 256) {
        int r = i / KDIM;
        int k = i - r * KDIM;
        int g = grp * 16 + r;
        float v = (k < NINP) ? w_ih[(size_t)g * NINP + k]
                             : w_hh[(size_t)g * NHID + (k - NINP)];
        int c = k >> 5, q = (k >> 3) & 3, e = k & 7;
        Wp[((size_t)grp * NCHUNK + c) * 512 + (q * 16 + r) * 8 + e] = f2b(v);
    }
    if (threadIdx.x < 16) {
        int g = grp * 16 + threadIdx.x;
        bias[g] = b_ih[g] + b_hh[g];
    }
}

__global__ void k_init(const int* __restrict__ tokens, const float* __restrict__ emb,
                       ushort_t* __restrict__ A0, int* __restrict__ sync) {
    int idx = blockIdx.x * 256 + threadIdx.x;
    if (idx < BATCH * KDIM) {
        int b = idx / KDIM, k = idx - b * KDIM;
        float v = (k < NINP) ? emb[tokens[b] * NINP + k] : 0.f;
        int c = k >> 5, q = (k >> 3) & 3, e = k & 7;
        A0[((size_t)(b >> 4) * NCHUNK + c) * 512 + (q * 16 + (b & 15)) * 8 + e] = f2b(v);
    }
    if (idx < SYNC_INTS) sync[idx] = 0;
}

// ---- persistent LSTM: all 256 steps in one cooperative launch ----
__global__ __launch_bounds__(512, 2)
void k_persist(const ushort_t* __restrict__ Wp, const float* __restrict__ bias,
               ushort_t* __restrict__ A0, ushort_t* __restrict__ A1,
               float* __restrict__ out,
               const int* __restrict__ tokens, const int* __restrict__ seq_len,
               const float* __restrict__ emb, int* __restrict__ sync) {
    const int tid  = threadIdx.x;
    const int wave = tid >> 6;
    const int lane = tid & 63;
    const int bx   = blockIdx.x;
    const int j0   = bx * 16;

    int* master_cnt = sync;
    int* master_gen = sync + 32;
    int* shard_cnt  = sync + 64  + 32 * (bx & 7);
    int* shard_gen  = sync + 320 + 32 * (bx & 7);

    __shared__ float sbuf[BATCH][66];

    // --- per-thread persistent state ---
    const int jA = j0 + wave, jB = j0 + wave + 8;
    float cA = 0.f, cB = 0.f;
    const int  slen = seq_len[lane];
    const float bAi = bias[jA],            bBi = bias[jB];
    const float bAf = bias[NHID + jA],     bBf = bias[NHID + jB];
    const float bAg = bias[2 * NHID + jA], bBg = bias[2 * NHID + jB];
    const float bAo = bias[3 * NHID + jA], bBo = bias[3 * NHID + jB];
    size_t hoffA, hoffB;
    {
        int kk = NINP + jA;
        int c = kk >> 5, q = (kk >> 3) & 3, e = kk & 7;
        hoffA = ((size_t)(lane >> 4) * NCHUNK + c) * 512 + (q * 16 + (lane & 15)) * 8 + e;
        kk = NINP + jB;
        c = kk >> 5; q = (kk >> 3) & 3; e = kk & 7;
        hoffB = ((size_t)(lane >> 4) * NCHUNK + c) * 512 + (q * 16 + (lane & 15)) * 8 + e;
    }

    const int cstart = wave * 16 + (wave < 2 ? wave : 2);
    const int cend   = cstart + (wave < 2 ? 17 : 16);

    const ushort_t* pw0 = Wp + ((size_t)(0 * 256 + bx) * NCHUNK) * 512 + lane * 8;
    const ushort_t* pw1 = Wp + ((size_t)(1 * 256 + bx) * NCHUNK) * 512 + lane * 8;
    const ushort_t* pw2 = Wp + ((size_t)(2 * 256 + bx) * NCHUNK) * 512 + lane * 8;
    const ushort_t* pw3 = Wp + ((size_t)(3 * 256 + bx) * NCHUNK) * 512 + lane * 8;

    for (int t = 0; t < TSTEPS; ++t) {
        ushort_t* Ac = (t & 1) ? A1 : A0;
        ushort_t* An = (t & 1) ? A0 : A1;

        for (int i = tid; i < BATCH * 66; i += 512)
            (&sbuf[0][0])[i] = 0.f;

        const ushort_t* pa0 = Ac + ((size_t)0 * NCHUNK) * 512 + lane * 8;
        const ushort_t* pa1 = Ac + ((size_t)1 * NCHUNK) * 512 + lane * 8;
        const ushort_t* pa2 = Ac + ((size_t)2 * NCHUNK) * 512 + lane * 8;
        const ushort_t* pa3 = Ac + ((size_t)3 * NCHUNK) * 512 + lane * 8;

        f32x4 acc[4][4];
        #pragma unroll
        for (int rt = 0; rt < 4; ++rt)
            #pragma unroll
            for (int gt = 0; gt < 4; ++gt)
                acc[rt][gt] = (f32x4){0.f, 0.f, 0.f, 0.f};

        #define LOADF(dstW, dstA, c)                                          \
            do {                                                              \
                size_t off = (size_t)(c) * 512;                               \
                dstW[0] = *reinterpret_cast<const bf16x8*>(pw0 + off);        \
                dstW[1] = *reinterpret_cast<const bf16x8*>(pw1 + off);        \
                dstW[2] = *reinterpret_cast<const bf16x8*>(pw2 + off);        \
                dstW[3] = *reinterpret_cast<const bf16x8*>(pw3 + off);        \
                dstA[0] = *reinterpret_cast<const bf16x8*>(pa0 + off);        \
                dstA[1] = *reinterpret_cast<const bf16x8*>(pa1 + off);        \
                dstA[2] = *reinterpret_cast<const bf16x8*>(pa2 + off);        \
                dstA[3] = *reinterpret_cast<const bf16x8*>(pa3 + off);        \
            } while (0)

        bf16x8 curW[4], curA[4], nxtW[4], nxtA[4];
        LOADF(curW, curA, cstart);

        __syncthreads();   // sbuf zeroed before any atomics land

        for (int c = cstart; c < cend - 1; ++c) {
            LOADF(nxtW, nxtA, c + 1);
            #pragma unroll
            for (int rt = 0; rt < 4; ++rt)
                #pragma unroll
                for (int gt = 0; gt < 4; ++gt)
                    acc[rt][gt] = __builtin_amdgcn_mfma_f32_16x16x32_bf16(
                        curA[rt], curW[gt], acc[rt][gt], 0, 0, 0);
            #pragma unroll
            for (int z = 0; z < 4; ++z) { curW[z] = nxtW[z]; curA[z] = nxtA[z]; }
        }
        #pragma unroll
        for (int rt = 0; rt < 4; ++rt)
            #pragma unroll
            for (int gt = 0; gt < 4; ++gt)
                acc[rt][gt] = __builtin_amdgcn_mfma_f32_16x16x32_bf16(
                    curA[rt], curW[gt], acc[rt][gt], 0, 0, 0);
        #undef LOADF

        {
            const int n = lane & 15, q = lane >> 4;
            #pragma unroll
            for (int rt = 0; rt < 4; ++rt)
                #pragma unroll
                for (int gt = 0; gt < 4; ++gt)
                    #pragma unroll
                    for (int r = 0; r < 4; ++r)
                        atomicAdd(&sbuf[rt * 16 + q * 4 + r][gt * 16 + n], acc[rt][gt][r]);
        }
        __syncthreads();

        // epilogue: batch b = lane, cols jl = wave, wave+8
        {
            const int b = lane;
            const bool valid = (t < slen) || (t == 0);
            {
                int jl = wave;
                float ig = sbuf[b][ 0 + jl] + bAi;
                float fg = sbuf[b][16 + jl] + bAf;
                float gg = sbuf[b][32 + jl] + bAg;
                float og = sbuf[b][48 + jl] + bAo;
                cA = sigf(fg) * cA + sigf(ig) * tanhf(gg);
                float hn = sigf(og) * tanhf(cA);
                if (valid) out[b * NHID + jA] = cA;
                An[hoffA] = f2b(hn);
            }
            {
                int jl = wave + 8;
                float ig = sbuf[b][ 0 + jl] + bBi;
                float fg = sbuf[b][16 + jl] + bBf;
                float gg = sbuf[b][32 + jl] + bBg;
                float og = sbuf[b][48 + jl] + bBo;
                cB = sigf(fg) * cB + sigf(ig) * tanhf(gg);
                float hn = sigf(og) * tanhf(cB);
                if (valid) out[b * NHID + jB] = cB;
                An[hoffB] = f2b(hn);
            }
        }

        if (bx == 0 && (t + 1) < TSTEPS) {
            for (int i = tid; i < BATCH * NINP; i += 512) {
                int b = i >> 6, k = i & 63;
                int tok = tokens[(t + 1) * BATCH + b];
                float v = emb[tok * NINP + k];
                int c = k >> 5, q = (k >> 3) & 3, e = k & 7;
                An[((size_t)(b >> 4) * NCHUNK + c) * 512 + (q * 16 + (b & 15)) * 8 + e] = f2b(v);
            }
        }

        // ---- hierarchical grid barrier (monotonic counters, sharded lines) ----
        if (t + 1 < TSTEPS) {
            __syncthreads();   // each wave drains its stores (vmcnt 0) before arrival
            if (tid == 0) {
                __threadfence();                           // release: L2 writeback
                const int g = t + 1;
                if (atomicAdd(shard_cnt, 1) == 32 * g - 1) {
                    // last block of this shard
                    if (atomicAdd(master_cnt, 1) == 8 * g - 1) {
                        __hip_atomic_store(master_gen, g, __ATOMIC_RELAXED,
                                           __HIP_MEMORY_SCOPE_AGENT);
                    } else {
                        while (__hip_atomic_load(master_gen, __ATOMIC_RELAXED,
                                                 __HIP_MEMORY_SCOPE_AGENT) < g)
                            __builtin_amdgcn_s_sleep(2);
                    }
                    __hip_atomic_store(shard_gen, g, __ATOMIC_RELAXED,
                                       __HIP_MEMORY_SCOPE_AGENT);
                } else {
                    while (__hip_atomic_load(shard_gen, __ATOMIC_RELAXED,
                                             __HIP_MEMORY_SCOPE_AGENT) < g)
                        __builtin_amdgcn_s_sleep(8);
                }
                __threadfence();                           // acquire: L2/L1 invalidate
            }
            __syncthreads();
        }
    }
}

extern "C" void kernel_launch(void* const* d_in, const int* in_sizes, int n_in,
                              void* d_out, int out_size, void* d_ws, size_t ws_size,
                              hipStream_t stream) {
    const int*   tokens  = (const int*)d_in[0];
    const int*   seq_len = (const int*)d_in[1];
    const float* emb     = (const float*)d_in[2];
    const float* w_ih    = (const float*)d_in[3];
    const float* w_hh    = (const float*)d_in[4];
    const float* b_ih    = (const float*)d_in[5];
    const float* b_hh    = (const float*)d_in[6];
    float* out = (float*)d_out;

    char* ws = (char*)d_ws;
    const size_t W_BYTES    = (size_t)NGRP * NCHUNK * 512 * 2;  // 136,314,880
    const size_t BIAS_BYTES = (size_t)NGATE * 4;
    const size_t A_BYTES    = (size_t)4 * NCHUNK * 512 * 2;     // 532,480

    ushort_t* Wp   = (ushort_t*)ws;
    float*    bias = (float*)(ws + W_BYTES);
    ushort_t* A0   = (ushort_t*)(ws + W_BYTES + BIAS_BYTES);
    ushort_t* A1   = (ushort_t*)(ws + W_BYTES + BIAS_BYTES + A_BYTES);
    int*      sync = (int*)(ws + W_BYTES + BIAS_BYTES + 2 * A_BYTES);

    k_convert<<<NGRP, 256, 0, stream>>>(w_ih, w_hh, b_ih, b_hh, Wp, bias);

    int init_elems = BATCH * KDIM;
    k_init<<<(init_elems + 255) / 256, 256, 0, stream>>>(tokens, emb, A0, sync);

    void* args[] = {(void*)&Wp, (void*)&bias, (void*)&A0, (void*)&A1, (void*)&out,
                    (void*)&tokens, (void*)&seq_len, (void*)&emb, (void*)&sync};
    hipLaunchCooperativeKernel((void*)k_persist, dim3(NBLK), dim3(512), args, 0, stream);
}